// Round 1
// baseline (101.669 us; speedup 1.0000x reference)
//
#include <hip/hip_runtime.h>

#define N_NODES 50000
#define N_EDGES 100000
#define DIM 64

// Kernel 1: init last-edge-index per node to -1
__global__ void init_last_kernel(int* __restrict__ last, int n) {
    int i = blockIdx.x * blockDim.x + threadIdx.x;
    if (i < n) last[i] = -1;
}

// Kernel 2: last_idx[dst] = max edge index with that dst
__global__ void edge_max_kernel(const int* __restrict__ edges,
                                int* __restrict__ last, int ne) {
    int e = blockIdx.x * blockDim.x + threadIdx.x;
    if (e < ne) {
        int dst = edges[e * 3 + 2];
        atomicMax(&last[dst], e);
    }
}

// Kernel 3: one wave per node; lane = output column.
// out[n] = h[n] @ W_self + (last>=0 ? h[src] @ weight[rel] : 0)
__global__ __launch_bounds__(256) void node_out_kernel(
    const float* __restrict__ h,
    const int* __restrict__ edges,
    const float* __restrict__ weight,
    const float* __restrict__ wself,
    const int* __restrict__ last,
    float* __restrict__ out,
    int nn)
{
    int wave = (blockIdx.x * blockDim.x + threadIdx.x) >> 6;
    int lane = threadIdx.x & 63;
    if (wave >= nn) return;
    const int n = wave;

    // Self-loop: each lane holds h[n][lane]; broadcast over i via shfl.
    float hval = h[n * DIM + lane];
    float acc = 0.f;
#pragma unroll
    for (int i = 0; i < DIM; ++i) {
        float hi = __shfl(hval, i);   // wave64 broadcast
        acc = fmaf(hi, wself[i * DIM + lane], acc);
    }

    int li = last[n];           // wave-uniform branch (one node per wave)
    if (li >= 0) {
        int s = edges[li * 3 + 0];
        int r = edges[li * 3 + 1];
        float sval = h[s * DIM + lane];
        const float* __restrict__ W = weight + (long)r * (DIM * DIM);
#pragma unroll
        for (int i = 0; i < DIM; ++i) {
            float si = __shfl(sval, i);
            acc = fmaf(si, W[i * DIM + lane], acc);
        }
    }
    out[n * DIM + lane] = acc;
}

extern "C" void kernel_launch(void* const* d_in, const int* in_sizes, int n_in,
                              void* d_out, int out_size, void* d_ws, size_t ws_size,
                              hipStream_t stream) {
    const float* h      = (const float*)d_in[0];   // (N_NODES, 64) f32
    const int*   edges  = (const int*)d_in[1];     // (N_EDGES, 3) i32 [src, rel, dst]
    const float* weight = (const float*)d_in[2];   // (200, 64, 64) f32
    const float* wself  = (const float*)d_in[3];   // (64, 64) f32
    float* out = (float*)d_out;
    int* last = (int*)d_ws;                         // N_NODES ints (200 KB)

    init_last_kernel<<<(N_NODES + 255) / 256, 256, 0, stream>>>(last, N_NODES);
    edge_max_kernel<<<(N_EDGES + 255) / 256, 256, 0, stream>>>(edges, last, N_EDGES);

    // one wave (64 lanes) per node, 4 waves per block
    int nblocks = (N_NODES + 3) / 4;
    node_out_kernel<<<nblocks, 256, 0, stream>>>(h, edges, weight, wself, last, out, N_NODES);
}